// Round 8
// baseline (1182.262 us; speedup 1.0000x reference)
//
#include <hip/hip_runtime.h>

// LapCluster MI355X — round 8: r7 MFMA pipeline + store_planes row fix.
// r7 bug: store_planes wrote D rows to quad*4+r, DROPPING the wave's Mt*16
// M-tile offset -> 4 waves raced into plane rows 0..15, rows 16..63 never
// written -> uninitialized LDS read as bf16 -> absmax inf. Fix: pass mt.
// Pipeline: 16x16x32 bf16 MFMA, 3-term split-bf16 (v=hi+lo truncated pair;
// A*B ~= AhBh+AhBl+AlBh, dropped AlBl ~2^-16 rel). Weights pre-split into
// fragment-ordered hi/lo arenas (prep kernel) -> B-frag = 2 coalesced
// dwordx4 from L2. Activations: LDS hi/lo bf16 planes, padded strides
// 136/72/40 (16B-aligned rows). Inter-kernel f3 packed (hi<<16)|lo u32.
// Frag layouts: A[m=lane&15][k=quad*8+j], B[k=quad*8+j][n=lane&15],
// D[row=quad*4+reg][col=lane&15]. Pool trick: W*[f3,pool] = W[:,:128]*f3 +
// poolc[o][cluster]; clusters in [0,16); ReLU>=0 -> u32 atomicMax exact.

typedef __attribute__((ext_vector_type(8))) short bf16x8;
typedef __attribute__((ext_vector_type(4))) float f32x4;

#define MFMA16(a, b, c) __builtin_amdgcn_mfma_f32_16x16x32_bf16((a), (b), (c), 0, 0, 0)

#define TPB 512
#define PT 64
#define NPTS 131072
#define NC 16
#define TILES 4
#define NBLK 512         // 64 blocks/batch

#define FSB 136          // 128-ch plane stride (bf16 units)
#define ASB 72           // 64-ch plane stride
#define XSB 40           // 32-ch (padded x) plane stride

// frag arena units (1 unit = 64 lanes * 8 dwords: [0..3]=hi frag, [4..7]=lo)
#define U_F256 0
#define U_W1_0 16
#define U_W2_0 48
#define U_W3_0 64
#define U_W1_1 96
#define U_W2_1 112
#define U_W3_1 128
#define U_W1_2 160
#define U_W2_2 176
#define U_W3_2 192
#define U_O1   224
#define U_O2   256
#define N_UNITS 288

__device__ __forceinline__ f32x4 relu4(f32x4 a) {
#pragma unroll
  for (int r = 0; r < 4; ++r) a[r] = fmaxf(a[r], 0.f);
  return a;
}

__device__ __forceinline__ bf16x8 afrag(const short* plane, int stride, int mt, int ks) {
  const int lane = threadIdx.x & 63;
  return *reinterpret_cast<const bf16x8*>(
      plane + (mt * 16 + (lane & 15)) * stride + ks * 32 + (lane >> 4) * 8);
}

__device__ __forceinline__ void bfrag(const unsigned* __restrict__ arena, int unit,
                                      bf16x8& h, bf16x8& l) {
  const bf16x8* p = reinterpret_cast<const bf16x8*>(
      arena + ((size_t)unit * 64 + (threadIdx.x & 63)) * 8);
  h = p[0];
  l = p[1];
}

// write already-relu'd D (4 regs = pts mt*16 + quad*4 + r) as hi/lo bf16
__device__ __forceinline__ void store_planes(short* hp, short* lp, int stride,
                                             int mt, int n, f32x4 d) {
  const int m0 = mt * 16 + ((threadIdx.x & 63) >> 4) * 4;   // FIX: + mt*16
#pragma unroll
  for (int r = 0; r < 4; ++r) {
    unsigned uv = __float_as_uint(d[r]);
    unsigned hm = uv & 0xFFFF0000u;
    float lo = d[r] - __uint_as_float(hm);
    hp[(m0 + r) * stride + n] = (short)(hm >> 16);
    lp[(m0 + r) * stride + n] = (short)(__float_as_uint(lo) >> 16);
  }
}

__device__ __forceinline__ unsigned packsplit(float v) {
  unsigned uv = __float_as_uint(v);
  unsigned hm = uv & 0xFFFF0000u;
  float lo = v - __uint_as_float(hm);
  return hm | (__float_as_uint(lo) >> 16);
}

// ---- prep: split weights into fragment-ordered hi/lo bf16 arenas
__global__ void __launch_bounds__(64) prep_frags(
    const float* __restrict__ w_in, const float* __restrict__ w1,
    const float* __restrict__ w2, const float* __restrict__ w3,
    const float* __restrict__ wo1, const float* __restrict__ wo2,
    unsigned* __restrict__ arena) {
  const int unit = blockIdx.x;
  const int lane = threadIdx.x;
  const float* W; int KS, Klog, rs, u;
  if (unit < U_W1_0)      { W = w_in;                   u = unit - U_F256; KS = 1; Klog = 28;  rs = 28;  }
  else if (unit < U_W2_0) { W = w1;                     u = unit - U_W1_0; KS = 8; Klog = 256; rs = 256; }
  else if (unit < U_W3_0) { W = w2;                     u = unit - U_W2_0; KS = 2; Klog = 64;  rs = 64;  }
  else if (unit < U_W1_1) { W = w3;                     u = unit - U_W3_0; KS = 4; Klog = 128; rs = 128; }
  else if (unit < U_W2_1) { W = w1 + 64 * 256;          u = unit - U_W1_1; KS = 4; Klog = 128; rs = 256; }
  else if (unit < U_W3_1) { W = w2 + 128 * 64;          u = unit - U_W2_1; KS = 2; Klog = 64;  rs = 64;  }
  else if (unit < U_W1_2) { W = w3 + 128 * 128;         u = unit - U_W3_1; KS = 4; Klog = 128; rs = 128; }
  else if (unit < U_W2_2) { W = w1 + 2 * 64 * 256;      u = unit - U_W1_2; KS = 4; Klog = 128; rs = 256; }
  else if (unit < U_W3_2) { W = w2 + 2 * 128 * 64;      u = unit - U_W2_2; KS = 2; Klog = 64;  rs = 64;  }
  else if (unit < U_O1)   { W = w3 + 2 * 128 * 128;     u = unit - U_W3_2; KS = 4; Klog = 128; rs = 128; }
  else if (unit < U_O2)   { W = wo1;                    u = unit - U_O1;   KS = 4; Klog = 128; rs = 256; }
  else                    { W = wo2;                    u = unit - U_O2;   KS = 4; Klog = 128; rs = 128; }
  const int nt = u / KS, ks = u % KS;
  const int n = nt * 16 + (lane & 15);
  const int k0 = ks * 32 + (lane >> 4) * 8;
  unsigned hiD[4], loD[4];
#pragma unroll
  for (int d = 0; d < 4; ++d) {
    unsigned hu[2], lu[2];
#pragma unroll
    for (int e = 0; e < 2; ++e) {
      const int k = k0 + d * 2 + e;
      float v = (k < Klog) ? W[(size_t)n * rs + k] : 0.f;
      unsigned uv = __float_as_uint(v);
      unsigned hm = uv & 0xFFFF0000u;
      float lo = v - __uint_as_float(hm);
      hu[e] = hm >> 16;
      lu[e] = __float_as_uint(lo) >> 16;
    }
    hiD[d] = hu[0] | (hu[1] << 16);
    loD[d] = lu[0] | (lu[1] << 16);
  }
  unsigned* dst = arena + ((size_t)unit * 64 + lane) * 8;
  *reinterpret_cast<uint4*>(dst)     = make_uint4(hiD[0], hiD[1], hiD[2], hiD[3]);
  *reinterpret_cast<uint4*>(dst + 4) = make_uint4(loD[0], loD[1], loD[2], loD[3]);
}

// ---- per-batch poolc table (fp32)
template<int O>
__global__ void __launch_bounds__(1024) pool_reduce_kern(
    const unsigned* __restrict__ part, const float* __restrict__ W,
    const float* __restrict__ bias, float* __restrict__ poolc_g) {
  __shared__ float pfL[2048];
  __shared__ float Wl[O * 129];
  const int tid = threadIdx.x;
  const int b = blockIdx.x;
  for (int i = tid; i < 2048; i += 1024) pfL[i] = __uint_as_float(part[b * 2048 + i]);
  for (int i = tid; i < O * 128; i += 1024) {
    const int o = i >> 7, k = i & 127;
    Wl[o * 129 + k] = W[o * 256 + 128 + k];
  }
  __syncthreads();
  constexpr int SH = (O == 64) ? 6 : 7;
  for (int e = tid; e < O * 16; e += 1024) {
    const int o = e & (O - 1);
    const int cl = e >> SH;
    float s = bias[o];
    const float* wr = &Wl[o * 129];
    const float* pr = &pfL[cl];
#pragma unroll 4
    for (int k = 0; k < 128; ++k) s = fmaf(wr[k], pr[k * 16], s);
    poolc_g[(size_t)b * (O * 16) + o * 16 + cl] = s;
  }
}

// ---- Stage 0: x -> f256 -> f64(w1[0]) -> f128(w2[0], pooled) -> f3_0(w3[0])
__global__ void __launch_bounds__(TPB, 4) k0_kern(
    const float* __restrict__ x, const int* __restrict__ cls,
    const float* __restrict__ b_in, const float* __restrict__ b1,
    const float* __restrict__ b2, const float* __restrict__ b3,
    const unsigned* __restrict__ arena,
    unsigned* __restrict__ f3g, unsigned* __restrict__ part0) {
  __shared__ short Fhi[PT * FSB], Flo[PT * FSB];
  __shared__ short XA[PT * ASB * 2];               // x planes alias A64 planes
  __shared__ unsigned pool_s[128 * NC];
  short* Xhi = XA;  short* Xlo = XA + PT * XSB;
  short* Ahi = XA;  short* Alo = XA + PT * ASB;
  const int tid = threadIdx.x;
  const int lane = tid & 63, w = tid >> 6, l15 = lane & 15, quad = lane >> 4;
  const int b = blockIdx.x >> 6;
  const int Mt = w & 3, Nt2 = w >> 2;
  for (int i = tid; i < 128 * NC; i += TPB) pool_s[i] = 0u;

  float biH[2][4], b1H[2], b2H[4], b3H[4];
#pragma unroll
  for (int c = 0; c < 2; ++c)
#pragma unroll
    for (int i = 0; i < 4; ++i) biH[c][i] = b_in[c * 128 + (Nt2 * 4 + i) * 16 + l15];
#pragma unroll
  for (int i = 0; i < 2; ++i) b1H[i] = b1[(Nt2 * 2 + i) * 16 + l15];
#pragma unroll
  for (int i = 0; i < 4; ++i) {
    b2H[i] = b2[(Nt2 * 4 + i) * 16 + l15];
    b3H[i] = b3[(Nt2 * 4 + i) * 16 + l15];
  }
  const int xpt = (tid < 448) ? tid / 7 : 0;
  const int xc4 = (tid < 448) ? (tid - xpt * 7) * 4 : 0;

  for (int t = 0; t < TILES; ++t) {
    const int tile0 = (blockIdx.x * TILES + t) * PT;
    if (tid < 448) {   // stage x hi/lo
      const float4 v = *reinterpret_cast<const float4*>(x + (size_t)(tile0 + xpt) * 28 + xc4);
      unsigned h0 = __float_as_uint(v.x) & 0xFFFF0000u, h1 = __float_as_uint(v.y) & 0xFFFF0000u;
      unsigned h2 = __float_as_uint(v.z) & 0xFFFF0000u, h3 = __float_as_uint(v.w) & 0xFFFF0000u;
      uint2 hd, ld;
      hd.x = (h0 >> 16) | h1;
      hd.y = (h2 >> 16) | h3;
      ld.x = (__float_as_uint(v.x - __uint_as_float(h0)) >> 16) |
             (__float_as_uint(v.y - __uint_as_float(h1)) & 0xFFFF0000u);
      ld.y = (__float_as_uint(v.z - __uint_as_float(h2)) >> 16) |
             (__float_as_uint(v.w - __uint_as_float(h3)) & 0xFFFF0000u);
      *reinterpret_cast<uint2*>(&Xhi[xpt * XSB + xc4]) = hd;
      *reinterpret_cast<uint2*>(&Xlo[xpt * XSB + xc4]) = ld;
    } else {           // zero k pads 28..31 (region aliased by A64 last tile)
      const int p = tid - 448;
      *reinterpret_cast<uint2*>(&Xhi[p * XSB + 28]) = make_uint2(0u, 0u);
      *reinterpret_cast<uint2*>(&Xlo[p * XSB + 28]) = make_uint2(0u, 0u);
    }
    __syncthreads();   // B1
    const bf16x8 xah = afrag(Xhi, XSB, Mt, 0), xal = afrag(Xlo, XSB, Mt, 0);
    f32x4 acc1[2];
#pragma unroll
    for (int i = 0; i < 2; ++i) acc1[i] = {b1H[i], b1H[i], b1H[i], b1H[i]};
#pragma unroll 1
    for (int c = 0; c < 2; ++c) {
      f32x4 f6[4];
#pragma unroll
      for (int i = 0; i < 4; ++i) {
        f6[i] = {biH[c][i], biH[c][i], biH[c][i], biH[c][i]};
        bf16x8 bh, bl;
        bfrag(arena, U_F256 + c * 8 + Nt2 * 4 + i, bh, bl);
        f6[i] = MFMA16(xal, bh, MFMA16(xah, bl, MFMA16(xah, bh, f6[i])));
      }
#pragma unroll
      for (int i = 0; i < 4; ++i)
        store_planes(Fhi, Flo, FSB, Mt, (Nt2 * 4 + i) * 16 + l15, relu4(f6[i]));
      __syncthreads();   // B2 / B4
#pragma unroll
      for (int ks = 0; ks < 4; ++ks) {
        const bf16x8 ah = afrag(Fhi, FSB, Mt, ks), al = afrag(Flo, FSB, Mt, ks);
#pragma unroll
        for (int i = 0; i < 2; ++i) {
          bf16x8 bh, bl;
          bfrag(arena, U_W1_0 + (Nt2 * 2 + i) * 8 + c * 4 + ks, bh, bl);
          acc1[i] = MFMA16(al, bh, MFMA16(ah, bl, MFMA16(ah, bh, acc1[i])));
        }
      }
      if (c == 1) {
#pragma unroll
        for (int i = 0; i < 2; ++i)
          store_planes(Ahi, Alo, ASB, Mt, (Nt2 * 2 + i) * 16 + l15, relu4(acc1[i]));
      }
      __syncthreads();   // B3 / B5
    }
    int cl0[4];
#pragma unroll
    for (int r = 0; r < 4; ++r) cl0[r] = cls[tile0 + Mt * 16 + quad * 4 + r];
    f32x4 f2[4];
#pragma unroll
    for (int i = 0; i < 4; ++i) f2[i] = {b2H[i], b2H[i], b2H[i], b2H[i]};
#pragma unroll
    for (int ks = 0; ks < 2; ++ks) {
      const bf16x8 ah = afrag(Ahi, ASB, Mt, ks), al = afrag(Alo, ASB, Mt, ks);
#pragma unroll
      for (int i = 0; i < 4; ++i) {
        bf16x8 bh, bl;
        bfrag(arena, U_W2_0 + (Nt2 * 4 + i) * 2 + ks, bh, bl);
        f2[i] = MFMA16(al, bh, MFMA16(ah, bl, MFMA16(ah, bh, f2[i])));
      }
    }
#pragma unroll
    for (int i = 0; i < 4; ++i) {
      const int n = (Nt2 * 4 + i) * 16 + l15;
      f32x4 d = relu4(f2[i]);
#pragma unroll
      for (int r = 0; r < 4; ++r)
        atomicMax(&pool_s[n * NC + cl0[r]], __float_as_uint(d[r]));
      store_planes(Fhi, Flo, FSB, Mt, n, d);
    }
    __syncthreads();   // B6
    f32x4 f3a[4];
#pragma unroll
    for (int i = 0; i < 4; ++i) f3a[i] = {b3H[i], b3H[i], b3H[i], b3H[i]};
#pragma unroll
    for (int ks = 0; ks < 4; ++ks) {
      const bf16x8 ah = afrag(Fhi, FSB, Mt, ks), al = afrag(Flo, FSB, Mt, ks);
#pragma unroll
      for (int i = 0; i < 4; ++i) {
        bf16x8 bh, bl;
        bfrag(arena, U_W3_0 + (Nt2 * 4 + i) * 4 + ks, bh, bl);
        f3a[i] = MFMA16(al, bh, MFMA16(ah, bl, MFMA16(ah, bh, f3a[i])));
      }
    }
#pragma unroll
    for (int i = 0; i < 4; ++i) {
      const int n = (Nt2 * 4 + i) * 16 + l15;
#pragma unroll
      for (int r = 0; r < 4; ++r)
        f3g[(size_t)(tile0 + Mt * 16 + quad * 4 + r) * 128 + n] =
            packsplit(fmaxf(f3a[i][r], 0.f));
    }
    // no end barrier: next x-stage touches XA only (A64 reads fenced by B6);
    // F rewritten only post-next-B2, fenced by next B1+B2.
  }
  for (int i = tid; i < 128 * NC; i += TPB)
    atomicMax(&part0[(size_t)b * 2048 + i], pool_s[i]);
}

// ---- Stages 1,2: f3 -> f64(w1+poolc) -> f128(w2, pooled) -> f3'(w3)
__global__ void __launch_bounds__(TPB, 4) kmid_kern(
    unsigned* __restrict__ f3g, const unsigned* __restrict__ arena,
    const float* __restrict__ poolc_g, unsigned* __restrict__ part_cur,
    const int* __restrict__ clg, const int* __restrict__ clp,
    const float* __restrict__ b2s, const float* __restrict__ b3s,
    int uW1, int uW2, int uW3) {
  __shared__ short Fhi[PT * FSB], Flo[PT * FSB];
  __shared__ short Ahi[PT * ASB], Alo[PT * ASB];
  __shared__ unsigned pool_s[128 * NC];
  const int tid = threadIdx.x;
  const int lane = tid & 63, w = tid >> 6, l15 = lane & 15, quad = lane >> 4;
  const int b = blockIdx.x >> 6;
  const int Mt = w & 3, Nt2 = w >> 2;
  for (int i = tid; i < 128 * NC; i += TPB) pool_s[i] = 0u;
  float b2H[4], b3H[4];
#pragma unroll
  for (int i = 0; i < 4; ++i) {
    b2H[i] = b2s[(Nt2 * 4 + i) * 16 + l15];
    b3H[i] = b3s[(Nt2 * 4 + i) * 16 + l15];
  }

  for (int t = 0; t < TILES; ++t) {
    const int tile0 = (blockIdx.x * TILES + t) * PT;
    {  // stage packed f3 -> hi/lo planes
      const uint4* src = reinterpret_cast<const uint4*>(f3g + (size_t)tile0 * 128);
#pragma unroll
      for (int rr = 0; rr < 4; ++rr) {
        const int idx = rr * TPB + tid;
        const uint4 p = src[idx];
        const int pt = idx >> 5, c4 = (idx & 31) * 4;
        uint2 hd, ld;
        hd.x = (p.y & 0xFFFF0000u) | (p.x >> 16);
        hd.y = (p.w & 0xFFFF0000u) | (p.z >> 16);
        ld.x = (p.y << 16) | (p.x & 0xFFFFu);
        ld.y = (p.w << 16) | (p.z & 0xFFFFu);
        *reinterpret_cast<uint2*>(&Fhi[pt * FSB + c4]) = hd;
        *reinterpret_cast<uint2*>(&Flo[pt * FSB + c4]) = ld;
      }
    }
    __syncthreads();   // B1
    int clG[4], clP[4];
#pragma unroll
    for (int r = 0; r < 4; ++r) {
      clG[r] = clg[tile0 + Mt * 16 + quad * 4 + r];
      clP[r] = clp[tile0 + Mt * 16 + quad * 4 + r];
    }
    f32x4 a1[2];
#pragma unroll
    for (int i = 0; i < 2; ++i) {
      const int n = (Nt2 * 2 + i) * 16 + l15;
#pragma unroll
      for (int r = 0; r < 4; ++r) a1[i][r] = poolc_g[(size_t)b * 1024 + n * 16 + clG[r]];
    }
#pragma unroll
    for (int ks = 0; ks < 4; ++ks) {
      const bf16x8 ah = afrag(Fhi, FSB, Mt, ks), al = afrag(Flo, FSB, Mt, ks);
#pragma unroll
      for (int i = 0; i < 2; ++i) {
        bf16x8 bh, bl;
        bfrag(arena, uW1 + (Nt2 * 2 + i) * 4 + ks, bh, bl);
        a1[i] = MFMA16(al, bh, MFMA16(ah, bl, MFMA16(ah, bh, a1[i])));
      }
    }
#pragma unroll
    for (int i = 0; i < 2; ++i)
      store_planes(Ahi, Alo, ASB, Mt, (Nt2 * 2 + i) * 16 + l15, relu4(a1[i]));
    __syncthreads();   // B2
    f32x4 f2[4];
#pragma unroll
    for (int i = 0; i < 4; ++i) f2[i] = {b2H[i], b2H[i], b2H[i], b2H[i]};
#pragma unroll
    for (int ks = 0; ks < 2; ++ks) {
      const bf16x8 ah = afrag(Ahi, ASB, Mt, ks), al = afrag(Alo, ASB, Mt, ks);
#pragma unroll
      for (int i = 0; i < 4; ++i) {
        bf16x8 bh, bl;
        bfrag(arena, uW2 + (Nt2 * 4 + i) * 2 + ks, bh, bl);
        f2[i] = MFMA16(al, bh, MFMA16(ah, bl, MFMA16(ah, bh, f2[i])));
      }
    }
#pragma unroll
    for (int i = 0; i < 4; ++i) {
      const int n = (Nt2 * 4 + i) * 16 + l15;
      f32x4 d = relu4(f2[i]);
#pragma unroll
      for (int r = 0; r < 4; ++r)
        atomicMax(&pool_s[n * NC + clP[r]], __float_as_uint(d[r]));
      store_planes(Fhi, Flo, FSB, Mt, n, d);
    }
    __syncthreads();   // B3
    f32x4 f3a[4];
#pragma unroll
    for (int i = 0; i < 4; ++i) f3a[i] = {b3H[i], b3H[i], b3H[i], b3H[i]};
#pragma unroll
    for (int ks = 0; ks < 4; ++ks) {
      const bf16x8 ah = afrag(Fhi, FSB, Mt, ks), al = afrag(Flo, FSB, Mt, ks);
#pragma unroll
      for (int i = 0; i < 4; ++i) {
        bf16x8 bh, bl;
        bfrag(arena, uW3 + (Nt2 * 4 + i) * 4 + ks, bh, bl);
        f3a[i] = MFMA16(al, bh, MFMA16(ah, bl, MFMA16(ah, bh, f3a[i])));
      }
    }
#pragma unroll
    for (int i = 0; i < 4; ++i) {
      const int n = (Nt2 * 4 + i) * 16 + l15;
#pragma unroll
      for (int r = 0; r < 4; ++r)
        f3g[(size_t)(tile0 + Mt * 16 + quad * 4 + r) * 128 + n] =
            packsplit(fmaxf(f3a[i][r], 0.f));
    }
    __syncthreads();   // B4: w3 F-reads done before next stage overwrites F
  }
  for (int i = tid; i < 128 * NC; i += TPB)
    atomicMax(&part_cur[(size_t)b * 2048 + i], pool_s[i]);
}

// ---- Head: f3_2 -> o1(wo1+poolco) -> o2(wo2) -> global max
__global__ void __launch_bounds__(TPB, 4) k3_kern(
    const unsigned* __restrict__ f3g, const unsigned* __restrict__ arena,
    const float* __restrict__ poolco_g, const int* __restrict__ clg,
    const float* __restrict__ bo2, unsigned* __restrict__ out) {
  __shared__ short Fhi[PT * FSB], Flo[PT * FSB];
  const int tid = threadIdx.x;
  const int lane = tid & 63, w = tid >> 6, l15 = lane & 15, quad = lane >> 4;
  const int b = blockIdx.x >> 6;
  const int Mt = w & 3, Nt2 = w >> 2;
  float bo2H[4];
#pragma unroll
  for (int i = 0; i < 4; ++i) bo2H[i] = bo2[(Nt2 * 4 + i) * 16 + l15];
  float omax[4] = {0.f, 0.f, 0.f, 0.f};

  for (int t = 0; t < TILES; ++t) {
    const int tile0 = (blockIdx.x * TILES + t) * PT;
    {
      const uint4* src = reinterpret_cast<const uint4*>(f3g + (size_t)tile0 * 128);
#pragma unroll
      for (int rr = 0; rr < 4; ++rr) {
        const int idx = rr * TPB + tid;
        const uint4 p = src[idx];
        const int pt = idx >> 5, c4 = (idx & 31) * 4;
        uint2 hd, ld;
        hd.x = (p.y & 0xFFFF0000u) | (p.x >> 16);
        hd.y = (p.w & 0xFFFF0000u) | (p.z >> 16);
        ld.x = (p.y << 16) | (p.x & 0xFFFFu);
        ld.y = (p.w << 16) | (p.z & 0xFFFFu);
        *reinterpret_cast<uint2*>(&Fhi[pt * FSB + c4]) = hd;
        *reinterpret_cast<uint2*>(&Flo[pt * FSB + c4]) = ld;
      }
    }
    __syncthreads();   // B1
    int clA[4];
#pragma unroll
    for (int r = 0; r < 4; ++r) clA[r] = clg[tile0 + Mt * 16 + quad * 4 + r];
    f32x4 o1a[4];
#pragma unroll
    for (int i = 0; i < 4; ++i) {
      const int n = (Nt2 * 4 + i) * 16 + l15;
#pragma unroll
      for (int r = 0; r < 4; ++r) o1a[i][r] = poolco_g[(size_t)b * 2048 + n * 16 + clA[r]];
    }
#pragma unroll
    for (int ks = 0; ks < 4; ++ks) {
      const bf16x8 ah = afrag(Fhi, FSB, Mt, ks), al = afrag(Flo, FSB, Mt, ks);
#pragma unroll
      for (int i = 0; i < 4; ++i) {
        bf16x8 bh, bl;
        bfrag(arena, U_O1 + (Nt2 * 4 + i) * 4 + ks, bh, bl);
        o1a[i] = MFMA16(al, bh, MFMA16(ah, bl, MFMA16(ah, bh, o1a[i])));
      }
    }
    __syncthreads();   // B2: o1 F-reads done
#pragma unroll
    for (int i = 0; i < 4; ++i)
      store_planes(Fhi, Flo, FSB, Mt, (Nt2 * 4 + i) * 16 + l15, relu4(o1a[i]));
    __syncthreads();   // B3: o1 staged
    f32x4 o2a[4];
#pragma unroll
    for (int i = 0; i < 4; ++i) o2a[i] = {bo2H[i], bo2H[i], bo2H[i], bo2H[i]};
#pragma unroll
    for (int ks = 0; ks < 4; ++ks) {
      const bf16x8 ah = afrag(Fhi, FSB, Mt, ks), al = afrag(Flo, FSB, Mt, ks);
#pragma unroll
      for (int i = 0; i < 4; ++i) {
        bf16x8 bh, bl;
        bfrag(arena, U_O2 + (Nt2 * 4 + i) * 4 + ks, bh, bl);
        o2a[i] = MFMA16(al, bh, MFMA16(ah, bl, MFMA16(ah, bh, o2a[i])));
      }
    }
#pragma unroll
    for (int i = 0; i < 4; ++i) {
      f32x4 d = relu4(o2a[i]);
      omax[i] = fmaxf(omax[i], fmaxf(fmaxf(d[0], d[1]), fmaxf(d[2], d[3])));
    }
    __syncthreads();   // B4: o2 F-reads done before next stage
  }
#pragma unroll
  for (int i = 0; i < 4; ++i) {
    float m = omax[i];
    m = fmaxf(m, __shfl_xor(m, 16));
    m = fmaxf(m, __shfl_xor(m, 32));
    if (lane < 16)
      atomicMax(&out[b * 128 + (Nt2 * 4 + i) * 16 + lane], __float_as_uint(m));
  }
}

extern "C" void kernel_launch(void* const* d_in, const int* in_sizes, int n_in,
                              void* d_out, int out_size, void* d_ws, size_t ws_size,
                              hipStream_t stream) {
  const float* x    = (const float*)d_in[0];
  const int*   cls  = (const int*)d_in[1];
  const float* w_in = (const float*)d_in[2];
  const float* b_in = (const float*)d_in[3];
  const float* w1   = (const float*)d_in[4];
  const float* b1   = (const float*)d_in[5];
  const float* w2   = (const float*)d_in[6];
  const float* b2   = (const float*)d_in[7];
  const float* w3   = (const float*)d_in[8];
  const float* b3   = (const float*)d_in[9];
  const float* wo1  = (const float*)d_in[10];
  const float* bo1  = (const float*)d_in[11];
  const float* wo2  = (const float*)d_in[12];
  const float* bo2  = (const float*)d_in[13];

  char* ws = (char*)d_ws;
  unsigned* f3g = (unsigned*)ws;                            // 64 MB packed hi|lo
  unsigned* part0 = (unsigned*)(ws + ((size_t)64 << 20));   // 3 x 8 KB
  unsigned* part1 = part0 + 8 * 2048;
  unsigned* part2 = part1 + 8 * 2048;
  float* poolc1 = (float*)(part2 + 8 * 2048);               // 8*1024
  float* poolc2 = poolc1 + 8 * 1024;
  float* poolco = poolc2 + 8 * 1024;                        // 8*2048
  unsigned* arena = (unsigned*)(poolco + 8 * 2048);         // 288*512 dwords

  hipMemsetAsync(d_out, 0, 1024 * sizeof(float), stream);
  hipMemsetAsync(part0, 0, 3 * 8 * 2048 * sizeof(unsigned), stream);

  prep_frags<<<N_UNITS, 64, 0, stream>>>(w_in, w1, w2, w3, wo1, wo2, arena);
  k0_kern<<<NBLK, TPB, 0, stream>>>(x, cls, b_in, b1, b2, b3, arena, f3g, part0);
  pool_reduce_kern<64><<<8, 1024, 0, stream>>>(part0, w1 + (size_t)64 * 256, b1 + 64, poolc1);
  kmid_kern<<<NBLK, TPB, 0, stream>>>(f3g, arena, poolc1, part1, cls, cls + NPTS,
                                      b2 + 128, b3 + 128, U_W1_1, U_W2_1, U_W3_1);
  pool_reduce_kern<64><<<8, 1024, 0, stream>>>(part1, w1 + (size_t)2 * 64 * 256, b1 + 128, poolc2);
  kmid_kern<<<NBLK, TPB, 0, stream>>>(f3g, arena, poolc2, part2, cls + NPTS, cls + 2 * NPTS,
                                      b2 + 256, b3 + 256, U_W1_2, U_W2_2, U_W3_2);
  pool_reduce_kern<128><<<8, 1024, 0, stream>>>(part2, wo1, bo1, poolco);
  k3_kern<<<NBLK, TPB, 0, stream>>>(f3g, arena, poolco, cls + 2 * NPTS, bo2, (unsigned*)d_out);
}

// Round 9
// 1127.077 us; speedup vs baseline: 1.0490x; 1.0490x over previous
//
#include <hip/hip_runtime.h>

// LapCluster MI355X — round 9: r8 MFMA pipeline + NON-TEMPORAL streaming.
// r8 post-mortem: kmid FETCH 526MB/WRITE 317MB vs ~130MB true working set.
// Cause: bfrag re-reads the weight arena from global per MFMA group per tile
// (~1.07 GB instr-level traffic/dispatch); streaming f3g reads/writes thrash
// the 4MB per-XCD L2 and evict arena lines between uses. Fix: nt hints
// (__builtin_nontemporal_*) on f3g tile loads/stores + x loads so streams
// don't allocate in L2 -> arena stays L2-resident.
// Pipeline (r8): 16x16x32 bf16 MFMA, 3-term split-bf16 (v=hi+lo truncated;
// A*B ~= AhBh+AhBl+AlBh). Weights pre-split fragment-ordered hi/lo arena.
// Activations: LDS hi/lo bf16 planes, strides 136/72/40. f3 packed
// (hi<<16)|lo u32. A[m=lane&15][k=quad*8+j], B[k=quad*8+j][n=lane&15],
// D[row=quad*4+reg][col=lane&15]. Pool trick: W*[f3,pool] = W[:,:128]*f3 +
// poolc[o][cluster]; clusters in [0,16); ReLU>=0 -> u32 atomicMax exact.

typedef __attribute__((ext_vector_type(8))) short bf16x8;
typedef __attribute__((ext_vector_type(4))) float f32x4;
typedef __attribute__((ext_vector_type(4))) unsigned u32x4;
typedef __attribute__((ext_vector_type(4))) float f32x4v;

#define MFMA16(a, b, c) __builtin_amdgcn_mfma_f32_16x16x32_bf16((a), (b), (c), 0, 0, 0)

#define TPB 512
#define PT 64
#define NPTS 131072
#define NC 16
#define TILES 4
#define NBLK 512         // 64 blocks/batch

#define FSB 136          // 128-ch plane stride (bf16 units)
#define ASB 72           // 64-ch plane stride
#define XSB 40           // 32-ch (padded x) plane stride

// frag arena units (1 unit = 64 lanes * 8 dwords: [0..3]=hi frag, [4..7]=lo)
#define U_F256 0
#define U_W1_0 16
#define U_W2_0 48
#define U_W3_0 64
#define U_W1_1 96
#define U_W2_1 112
#define U_W3_1 128
#define U_W1_2 160
#define U_W2_2 176
#define U_W3_2 192
#define U_O1   224
#define U_O2   256
#define N_UNITS 288

__device__ __forceinline__ f32x4 relu4(f32x4 a) {
#pragma unroll
  for (int r = 0; r < 4; ++r) a[r] = fmaxf(a[r], 0.f);
  return a;
}

__device__ __forceinline__ bf16x8 afrag(const short* plane, int stride, int mt, int ks) {
  const int lane = threadIdx.x & 63;
  return *reinterpret_cast<const bf16x8*>(
      plane + (mt * 16 + (lane & 15)) * stride + ks * 32 + (lane >> 4) * 8);
}

__device__ __forceinline__ void bfrag(const unsigned* __restrict__ arena, int unit,
                                      bf16x8& h, bf16x8& l) {
  const bf16x8* p = reinterpret_cast<const bf16x8*>(
      arena + ((size_t)unit * 64 + (threadIdx.x & 63)) * 8);
  h = p[0];
  l = p[1];
}

// write already-relu'd D (4 regs = pts mt*16 + quad*4 + r) as hi/lo bf16
__device__ __forceinline__ void store_planes(short* hp, short* lp, int stride,
                                             int mt, int n, f32x4 d) {
  const int m0 = mt * 16 + ((threadIdx.x & 63) >> 4) * 4;
#pragma unroll
  for (int r = 0; r < 4; ++r) {
    unsigned uv = __float_as_uint(d[r]);
    unsigned hm = uv & 0xFFFF0000u;
    float lo = d[r] - __uint_as_float(hm);
    hp[(m0 + r) * stride + n] = (short)(hm >> 16);
    lp[(m0 + r) * stride + n] = (short)(__float_as_uint(lo) >> 16);
  }
}

__device__ __forceinline__ unsigned packsplit(float v) {
  unsigned uv = __float_as_uint(v);
  unsigned hm = uv & 0xFFFF0000u;
  float lo = v - __uint_as_float(hm);
  return hm | (__float_as_uint(lo) >> 16);
}

// ---- prep: split weights into fragment-ordered hi/lo bf16 arenas
__global__ void __launch_bounds__(64) prep_frags(
    const float* __restrict__ w_in, const float* __restrict__ w1,
    const float* __restrict__ w2, const float* __restrict__ w3,
    const float* __restrict__ wo1, const float* __restrict__ wo2,
    unsigned* __restrict__ arena) {
  const int unit = blockIdx.x;
  const int lane = threadIdx.x;
  const float* W; int KS, Klog, rs, u;
  if (unit < U_W1_0)      { W = w_in;                   u = unit - U_F256; KS = 1; Klog = 28;  rs = 28;  }
  else if (unit < U_W2_0) { W = w1;                     u = unit - U_W1_0; KS = 8; Klog = 256; rs = 256; }
  else if (unit < U_W3_0) { W = w2;                     u = unit - U_W2_0; KS = 2; Klog = 64;  rs = 64;  }
  else if (unit < U_W1_1) { W = w3;                     u = unit - U_W3_0; KS = 4; Klog = 128; rs = 128; }
  else if (unit < U_W2_1) { W = w1 + 64 * 256;          u = unit - U_W1_1; KS = 4; Klog = 128; rs = 256; }
  else if (unit < U_W3_1) { W = w2 + 128 * 64;          u = unit - U_W2_1; KS = 2; Klog = 64;  rs = 64;  }
  else if (unit < U_W1_2) { W = w3 + 128 * 128;         u = unit - U_W3_1; KS = 4; Klog = 128; rs = 128; }
  else if (unit < U_W2_2) { W = w1 + 2 * 64 * 256;      u = unit - U_W1_2; KS = 4; Klog = 128; rs = 256; }
  else if (unit < U_W3_2) { W = w2 + 2 * 128 * 64;      u = unit - U_W2_2; KS = 2; Klog = 64;  rs = 64;  }
  else if (unit < U_O1)   { W = w3 + 2 * 128 * 128;     u = unit - U_W3_2; KS = 4; Klog = 128; rs = 128; }
  else if (unit < U_O2)   { W = wo1;                    u = unit - U_O1;   KS = 4; Klog = 128; rs = 256; }
  else                    { W = wo2;                    u = unit - U_O2;   KS = 4; Klog = 128; rs = 128; }
  const int nt = u / KS, ks = u % KS;
  const int n = nt * 16 + (lane & 15);
  const int k0 = ks * 32 + (lane >> 4) * 8;
  unsigned hiD[4], loD[4];
#pragma unroll
  for (int d = 0; d < 4; ++d) {
    unsigned hu[2], lu[2];
#pragma unroll
    for (int e = 0; e < 2; ++e) {
      const int k = k0 + d * 2 + e;
      float v = (k < Klog) ? W[(size_t)n * rs + k] : 0.f;
      unsigned uv = __float_as_uint(v);
      unsigned hm = uv & 0xFFFF0000u;
      float lo = v - __uint_as_float(hm);
      hu[e] = hm >> 16;
      lu[e] = __float_as_uint(lo) >> 16;
    }
    hiD[d] = hu[0] | (hu[1] << 16);
    loD[d] = lu[0] | (lu[1] << 16);
  }
  unsigned* dst = arena + ((size_t)unit * 64 + lane) * 8;
  *reinterpret_cast<uint4*>(dst)     = make_uint4(hiD[0], hiD[1], hiD[2], hiD[3]);
  *reinterpret_cast<uint4*>(dst + 4) = make_uint4(loD[0], loD[1], loD[2], loD[3]);
}

// ---- per-batch poolc table (fp32)
template<int O>
__global__ void __launch_bounds__(1024) pool_reduce_kern(
    const unsigned* __restrict__ part, const float* __restrict__ W,
    const float* __restrict__ bias, float* __restrict__ poolc_g) {
  __shared__ float pfL[2048];
  __shared__ float Wl[O * 129];
  const int tid = threadIdx.x;
  const int b = blockIdx.x;
  for (int i = tid; i < 2048; i += 1024) pfL[i] = __uint_as_float(part[b * 2048 + i]);
  for (int i = tid; i < O * 128; i += 1024) {
    const int o = i >> 7, k = i & 127;
    Wl[o * 129 + k] = W[o * 256 + 128 + k];
  }
  __syncthreads();
  constexpr int SH = (O == 64) ? 6 : 7;
  for (int e = tid; e < O * 16; e += 1024) {
    const int o = e & (O - 1);
    const int cl = e >> SH;
    float s = bias[o];
    const float* wr = &Wl[o * 129];
    const float* pr = &pfL[cl];
#pragma unroll 4
    for (int k = 0; k < 128; ++k) s = fmaf(wr[k], pr[k * 16], s);
    poolc_g[(size_t)b * (O * 16) + o * 16 + cl] = s;
  }
}

// ---- Stage 0: x -> f256 -> f64(w1[0]) -> f128(w2[0], pooled) -> f3_0(w3[0])
__global__ void __launch_bounds__(TPB, 4) k0_kern(
    const float* __restrict__ x, const int* __restrict__ cls,
    const float* __restrict__ b_in, const float* __restrict__ b1,
    const float* __restrict__ b2, const float* __restrict__ b3,
    const unsigned* __restrict__ arena,
    unsigned* __restrict__ f3g, unsigned* __restrict__ part0) {
  __shared__ short Fhi[PT * FSB], Flo[PT * FSB];
  __shared__ short XA[PT * ASB * 2];               // x planes alias A64 planes
  __shared__ unsigned pool_s[128 * NC];
  short* Xhi = XA;  short* Xlo = XA + PT * XSB;
  short* Ahi = XA;  short* Alo = XA + PT * ASB;
  const int tid = threadIdx.x;
  const int lane = tid & 63, w = tid >> 6, l15 = lane & 15, quad = lane >> 4;
  const int b = blockIdx.x >> 6;
  const int Mt = w & 3, Nt2 = w >> 2;
  for (int i = tid; i < 128 * NC; i += TPB) pool_s[i] = 0u;

  float biH[2][4], b1H[2], b2H[4], b3H[4];
#pragma unroll
  for (int c = 0; c < 2; ++c)
#pragma unroll
    for (int i = 0; i < 4; ++i) biH[c][i] = b_in[c * 128 + (Nt2 * 4 + i) * 16 + l15];
#pragma unroll
  for (int i = 0; i < 2; ++i) b1H[i] = b1[(Nt2 * 2 + i) * 16 + l15];
#pragma unroll
  for (int i = 0; i < 4; ++i) {
    b2H[i] = b2[(Nt2 * 4 + i) * 16 + l15];
    b3H[i] = b3[(Nt2 * 4 + i) * 16 + l15];
  }
  const int xpt = (tid < 448) ? tid / 7 : 0;
  const int xc4 = (tid < 448) ? (tid - xpt * 7) * 4 : 0;

  for (int t = 0; t < TILES; ++t) {
    const int tile0 = (blockIdx.x * TILES + t) * PT;
    if (tid < 448) {   // stage x hi/lo (nt load: don't pollute L2)
      const f32x4v v = __builtin_nontemporal_load(
          reinterpret_cast<const f32x4v*>(x + (size_t)(tile0 + xpt) * 28 + xc4));
      unsigned h0 = __float_as_uint(v.x) & 0xFFFF0000u, h1 = __float_as_uint(v.y) & 0xFFFF0000u;
      unsigned h2 = __float_as_uint(v.z) & 0xFFFF0000u, h3 = __float_as_uint(v.w) & 0xFFFF0000u;
      uint2 hd, ld;
      hd.x = (h0 >> 16) | h1;
      hd.y = (h2 >> 16) | h3;
      ld.x = (__float_as_uint(v.x - __uint_as_float(h0)) >> 16) |
             (__float_as_uint(v.y - __uint_as_float(h1)) & 0xFFFF0000u);
      ld.y = (__float_as_uint(v.z - __uint_as_float(h2)) >> 16) |
             (__float_as_uint(v.w - __uint_as_float(h3)) & 0xFFFF0000u);
      *reinterpret_cast<uint2*>(&Xhi[xpt * XSB + xc4]) = hd;
      *reinterpret_cast<uint2*>(&Xlo[xpt * XSB + xc4]) = ld;
    } else {           // zero k pads 28..31 (region aliased by A64 last tile)
      const int p = tid - 448;
      *reinterpret_cast<uint2*>(&Xhi[p * XSB + 28]) = make_uint2(0u, 0u);
      *reinterpret_cast<uint2*>(&Xlo[p * XSB + 28]) = make_uint2(0u, 0u);
    }
    __syncthreads();   // B1
    const bf16x8 xah = afrag(Xhi, XSB, Mt, 0), xal = afrag(Xlo, XSB, Mt, 0);
    f32x4 acc1[2];
#pragma unroll
    for (int i = 0; i < 2; ++i) acc1[i] = {b1H[i], b1H[i], b1H[i], b1H[i]};
#pragma unroll 1
    for (int c = 0; c < 2; ++c) {
      f32x4 f6[4];
#pragma unroll
      for (int i = 0; i < 4; ++i) {
        f6[i] = {biH[c][i], biH[c][i], biH[c][i], biH[c][i]};
        bf16x8 bh, bl;
        bfrag(arena, U_F256 + c * 8 + Nt2 * 4 + i, bh, bl);
        f6[i] = MFMA16(xal, bh, MFMA16(xah, bl, MFMA16(xah, bh, f6[i])));
      }
#pragma unroll
      for (int i = 0; i < 4; ++i)
        store_planes(Fhi, Flo, FSB, Mt, (Nt2 * 4 + i) * 16 + l15, relu4(f6[i]));
      __syncthreads();   // B2 / B4
#pragma unroll
      for (int ks = 0; ks < 4; ++ks) {
        const bf16x8 ah = afrag(Fhi, FSB, Mt, ks), al = afrag(Flo, FSB, Mt, ks);
#pragma unroll
        for (int i = 0; i < 2; ++i) {
          bf16x8 bh, bl;
          bfrag(arena, U_W1_0 + (Nt2 * 2 + i) * 8 + c * 4 + ks, bh, bl);
          acc1[i] = MFMA16(al, bh, MFMA16(ah, bl, MFMA16(ah, bh, acc1[i])));
        }
      }
      if (c == 1) {
#pragma unroll
        for (int i = 0; i < 2; ++i)
          store_planes(Ahi, Alo, ASB, Mt, (Nt2 * 2 + i) * 16 + l15, relu4(acc1[i]));
      }
      __syncthreads();   // B3 / B5
    }
    int cl0[4];
#pragma unroll
    for (int r = 0; r < 4; ++r) cl0[r] = cls[tile0 + Mt * 16 + quad * 4 + r];
    f32x4 f2[4];
#pragma unroll
    for (int i = 0; i < 4; ++i) f2[i] = {b2H[i], b2H[i], b2H[i], b2H[i]};
#pragma unroll
    for (int ks = 0; ks < 2; ++ks) {
      const bf16x8 ah = afrag(Ahi, ASB, Mt, ks), al = afrag(Alo, ASB, Mt, ks);
#pragma unroll
      for (int i = 0; i < 4; ++i) {
        bf16x8 bh, bl;
        bfrag(arena, U_W2_0 + (Nt2 * 4 + i) * 2 + ks, bh, bl);
        f2[i] = MFMA16(al, bh, MFMA16(ah, bl, MFMA16(ah, bh, f2[i])));
      }
    }
#pragma unroll
    for (int i = 0; i < 4; ++i) {
      const int n = (Nt2 * 4 + i) * 16 + l15;
      f32x4 d = relu4(f2[i]);
#pragma unroll
      for (int r = 0; r < 4; ++r)
        atomicMax(&pool_s[n * NC + cl0[r]], __float_as_uint(d[r]));
      store_planes(Fhi, Flo, FSB, Mt, n, d);
    }
    __syncthreads();   // B6
    f32x4 f3a[4];
#pragma unroll
    for (int i = 0; i < 4; ++i) f3a[i] = {b3H[i], b3H[i], b3H[i], b3H[i]};
#pragma unroll
    for (int ks = 0; ks < 4; ++ks) {
      const bf16x8 ah = afrag(Fhi, FSB, Mt, ks), al = afrag(Flo, FSB, Mt, ks);
#pragma unroll
      for (int i = 0; i < 4; ++i) {
        bf16x8 bh, bl;
        bfrag(arena, U_W3_0 + (Nt2 * 4 + i) * 4 + ks, bh, bl);
        f3a[i] = MFMA16(al, bh, MFMA16(ah, bl, MFMA16(ah, bh, f3a[i])));
      }
    }
#pragma unroll
    for (int i = 0; i < 4; ++i) {
      const int n = (Nt2 * 4 + i) * 16 + l15;
#pragma unroll
      for (int r = 0; r < 4; ++r)
        __builtin_nontemporal_store(
            packsplit(fmaxf(f3a[i][r], 0.f)),
            &f3g[(size_t)(tile0 + Mt * 16 + quad * 4 + r) * 128 + n]);
    }
    // no end barrier: next x-stage touches XA only (A64 reads fenced by B6);
    // F rewritten only post-next-B2, fenced by next B1+B2.
  }
  for (int i = tid; i < 128 * NC; i += TPB)
    atomicMax(&part0[(size_t)b * 2048 + i], pool_s[i]);
}

// ---- Stages 1,2: f3 -> f64(w1+poolc) -> f128(w2, pooled) -> f3'(w3)
__global__ void __launch_bounds__(TPB, 4) kmid_kern(
    unsigned* __restrict__ f3g, const unsigned* __restrict__ arena,
    const float* __restrict__ poolc_g, unsigned* __restrict__ part_cur,
    const int* __restrict__ clg, const int* __restrict__ clp,
    const float* __restrict__ b2s, const float* __restrict__ b3s,
    int uW1, int uW2, int uW3) {
  __shared__ short Fhi[PT * FSB], Flo[PT * FSB];
  __shared__ short Ahi[PT * ASB], Alo[PT * ASB];
  __shared__ unsigned pool_s[128 * NC];
  const int tid = threadIdx.x;
  const int lane = tid & 63, w = tid >> 6, l15 = lane & 15, quad = lane >> 4;
  const int b = blockIdx.x >> 6;
  const int Mt = w & 3, Nt2 = w >> 2;
  for (int i = tid; i < 128 * NC; i += TPB) pool_s[i] = 0u;
  float b2H[4], b3H[4];
#pragma unroll
  for (int i = 0; i < 4; ++i) {
    b2H[i] = b2s[(Nt2 * 4 + i) * 16 + l15];
    b3H[i] = b3s[(Nt2 * 4 + i) * 16 + l15];
  }

  for (int t = 0; t < TILES; ++t) {
    const int tile0 = (blockIdx.x * TILES + t) * PT;
    {  // stage packed f3 -> hi/lo planes (nt loads: streaming)
      const u32x4* src = reinterpret_cast<const u32x4*>(f3g + (size_t)tile0 * 128);
#pragma unroll
      for (int rr = 0; rr < 4; ++rr) {
        const int idx = rr * TPB + tid;
        const u32x4 p = __builtin_nontemporal_load(src + idx);
        const int pt = idx >> 5, c4 = (idx & 31) * 4;
        uint2 hd, ld;
        hd.x = (p.y & 0xFFFF0000u) | (p.x >> 16);
        hd.y = (p.w & 0xFFFF0000u) | (p.z >> 16);
        ld.x = (p.y << 16) | (p.x & 0xFFFFu);
        ld.y = (p.w << 16) | (p.z & 0xFFFFu);
        *reinterpret_cast<uint2*>(&Fhi[pt * FSB + c4]) = hd;
        *reinterpret_cast<uint2*>(&Flo[pt * FSB + c4]) = ld;
      }
    }
    __syncthreads();   // B1
    int clG[4], clP[4];
#pragma unroll
    for (int r = 0; r < 4; ++r) {
      clG[r] = clg[tile0 + Mt * 16 + quad * 4 + r];
      clP[r] = clp[tile0 + Mt * 16 + quad * 4 + r];
    }
    f32x4 a1[2];
#pragma unroll
    for (int i = 0; i < 2; ++i) {
      const int n = (Nt2 * 2 + i) * 16 + l15;
#pragma unroll
      for (int r = 0; r < 4; ++r) a1[i][r] = poolc_g[(size_t)b * 1024 + n * 16 + clG[r]];
    }
#pragma unroll
    for (int ks = 0; ks < 4; ++ks) {
      const bf16x8 ah = afrag(Fhi, FSB, Mt, ks), al = afrag(Flo, FSB, Mt, ks);
#pragma unroll
      for (int i = 0; i < 2; ++i) {
        bf16x8 bh, bl;
        bfrag(arena, uW1 + (Nt2 * 2 + i) * 4 + ks, bh, bl);
        a1[i] = MFMA16(al, bh, MFMA16(ah, bl, MFMA16(ah, bh, a1[i])));
      }
    }
#pragma unroll
    for (int i = 0; i < 2; ++i)
      store_planes(Ahi, Alo, ASB, Mt, (Nt2 * 2 + i) * 16 + l15, relu4(a1[i]));
    __syncthreads();   // B2
    f32x4 f2[4];
#pragma unroll
    for (int i = 0; i < 4; ++i) f2[i] = {b2H[i], b2H[i], b2H[i], b2H[i]};
#pragma unroll
    for (int ks = 0; ks < 2; ++ks) {
      const bf16x8 ah = afrag(Ahi, ASB, Mt, ks), al = afrag(Alo, ASB, Mt, ks);
#pragma unroll
      for (int i = 0; i < 4; ++i) {
        bf16x8 bh, bl;
        bfrag(arena, uW2 + (Nt2 * 4 + i) * 2 + ks, bh, bl);
        f2[i] = MFMA16(al, bh, MFMA16(ah, bl, MFMA16(ah, bh, f2[i])));
      }
    }
#pragma unroll
    for (int i = 0; i < 4; ++i) {
      const int n = (Nt2 * 4 + i) * 16 + l15;
      f32x4 d = relu4(f2[i]);
#pragma unroll
      for (int r = 0; r < 4; ++r)
        atomicMax(&pool_s[n * NC + clP[r]], __float_as_uint(d[r]));
      store_planes(Fhi, Flo, FSB, Mt, n, d);
    }
    __syncthreads();   // B3
    f32x4 f3a[4];
#pragma unroll
    for (int i = 0; i < 4; ++i) f3a[i] = {b3H[i], b3H[i], b3H[i], b3H[i]};
#pragma unroll
    for (int ks = 0; ks < 4; ++ks) {
      const bf16x8 ah = afrag(Fhi, FSB, Mt, ks), al = afrag(Flo, FSB, Mt, ks);
#pragma unroll
      for (int i = 0; i < 4; ++i) {
        bf16x8 bh, bl;
        bfrag(arena, uW3 + (Nt2 * 4 + i) * 4 + ks, bh, bl);
        f3a[i] = MFMA16(al, bh, MFMA16(ah, bl, MFMA16(ah, bh, f3a[i])));
      }
    }
#pragma unroll
    for (int i = 0; i < 4; ++i) {
      const int n = (Nt2 * 4 + i) * 16 + l15;
#pragma unroll
      for (int r = 0; r < 4; ++r)
        __builtin_nontemporal_store(
            packsplit(fmaxf(f3a[i][r], 0.f)),
            &f3g[(size_t)(tile0 + Mt * 16 + quad * 4 + r) * 128 + n]);
    }
    __syncthreads();   // B4: w3 F-reads done before next stage overwrites F
  }
  for (int i = tid; i < 128 * NC; i += TPB)
    atomicMax(&part_cur[(size_t)b * 2048 + i], pool_s[i]);
}

// ---- Head: f3_2 -> o1(wo1+poolco) -> o2(wo2) -> global max
__global__ void __launch_bounds__(TPB, 4) k3_kern(
    const unsigned* __restrict__ f3g, const unsigned* __restrict__ arena,
    const float* __restrict__ poolco_g, const int* __restrict__ clg,
    const float* __restrict__ bo2, unsigned* __restrict__ out) {
  __shared__ short Fhi[PT * FSB], Flo[PT * FSB];
  const int tid = threadIdx.x;
  const int lane = tid & 63, w = tid >> 6, l15 = lane & 15, quad = lane >> 4;
  const int b = blockIdx.x >> 6;
  const int Mt = w & 3, Nt2 = w >> 2;
  float bo2H[4];
#pragma unroll
  for (int i = 0; i < 4; ++i) bo2H[i] = bo2[(Nt2 * 4 + i) * 16 + l15];
  float omax[4] = {0.f, 0.f, 0.f, 0.f};

  for (int t = 0; t < TILES; ++t) {
    const int tile0 = (blockIdx.x * TILES + t) * PT;
    {
      const u32x4* src = reinterpret_cast<const u32x4*>(f3g + (size_t)tile0 * 128);
#pragma unroll
      for (int rr = 0; rr < 4; ++rr) {
        const int idx = rr * TPB + tid;
        const u32x4 p = __builtin_nontemporal_load(src + idx);
        const int pt = idx >> 5, c4 = (idx & 31) * 4;
        uint2 hd, ld;
        hd.x = (p.y & 0xFFFF0000u) | (p.x >> 16);
        hd.y = (p.w & 0xFFFF0000u) | (p.z >> 16);
        ld.x = (p.y << 16) | (p.x & 0xFFFFu);
        ld.y = (p.w << 16) | (p.z & 0xFFFFu);
        *reinterpret_cast<uint2*>(&Fhi[pt * FSB + c4]) = hd;
        *reinterpret_cast<uint2*>(&Flo[pt * FSB + c4]) = ld;
      }
    }
    __syncthreads();   // B1
    int clA[4];
#pragma unroll
    for (int r = 0; r < 4; ++r) clA[r] = clg[tile0 + Mt * 16 + quad * 4 + r];
    f32x4 o1a[4];
#pragma unroll
    for (int i = 0; i < 4; ++i) {
      const int n = (Nt2 * 4 + i) * 16 + l15;
#pragma unroll
      for (int r = 0; r < 4; ++r) o1a[i][r] = poolco_g[(size_t)b * 2048 + n * 16 + clA[r]];
    }
#pragma unroll
    for (int ks = 0; ks < 4; ++ks) {
      const bf16x8 ah = afrag(Fhi, FSB, Mt, ks), al = afrag(Flo, FSB, Mt, ks);
#pragma unroll
      for (int i = 0; i < 4; ++i) {
        bf16x8 bh, bl;
        bfrag(arena, U_O1 + (Nt2 * 4 + i) * 4 + ks, bh, bl);
        o1a[i] = MFMA16(al, bh, MFMA16(ah, bl, MFMA16(ah, bh, o1a[i])));
      }
    }
    __syncthreads();   // B2: o1 F-reads done
#pragma unroll
    for (int i = 0; i < 4; ++i)
      store_planes(Fhi, Flo, FSB, Mt, (Nt2 * 4 + i) * 16 + l15, relu4(o1a[i]));
    __syncthreads();   // B3: o1 staged
    f32x4 o2a[4];
#pragma unroll
    for (int i = 0; i < 4; ++i) o2a[i] = {bo2H[i], bo2H[i], bo2H[i], bo2H[i]};
#pragma unroll
    for (int ks = 0; ks < 4; ++ks) {
      const bf16x8 ah = afrag(Fhi, FSB, Mt, ks), al = afrag(Flo, FSB, Mt, ks);
#pragma unroll
      for (int i = 0; i < 4; ++i) {
        bf16x8 bh, bl;
        bfrag(arena, U_O2 + (Nt2 * 4 + i) * 4 + ks, bh, bl);
        o2a[i] = MFMA16(al, bh, MFMA16(ah, bl, MFMA16(ah, bh, o2a[i])));
      }
    }
#pragma unroll
    for (int i = 0; i < 4; ++i) {
      f32x4 d = relu4(o2a[i]);
      omax[i] = fmaxf(omax[i], fmaxf(fmaxf(d[0], d[1]), fmaxf(d[2], d[3])));
    }
    __syncthreads();   // B4: o2 F-reads done before next stage
  }
#pragma unroll
  for (int i = 0; i < 4; ++i) {
    float m = omax[i];
    m = fmaxf(m, __shfl_xor(m, 16));
    m = fmaxf(m, __shfl_xor(m, 32));
    if (lane < 16)
      atomicMax(&out[b * 128 + (Nt2 * 4 + i) * 16 + lane], __float_as_uint(m));
  }
}

extern "C" void kernel_launch(void* const* d_in, const int* in_sizes, int n_in,
                              void* d_out, int out_size, void* d_ws, size_t ws_size,
                              hipStream_t stream) {
  const float* x    = (const float*)d_in[0];
  const int*   cls  = (const int*)d_in[1];
  const float* w_in = (const float*)d_in[2];
  const float* b_in = (const float*)d_in[3];
  const float* w1   = (const float*)d_in[4];
  const float* b1   = (const float*)d_in[5];
  const float* w2   = (const float*)d_in[6];
  const float* b2   = (const float*)d_in[7];
  const float* w3   = (const float*)d_in[8];
  const float* b3   = (const float*)d_in[9];
  const float* wo1  = (const float*)d_in[10];
  const float* bo1  = (const float*)d_in[11];
  const float* wo2  = (const float*)d_in[12];
  const float* bo2  = (const float*)d_in[13];

  char* ws = (char*)d_ws;
  unsigned* f3g = (unsigned*)ws;                            // 64 MB packed hi|lo
  unsigned* part0 = (unsigned*)(ws + ((size_t)64 << 20));   // 3 x 8 KB
  unsigned* part1 = part0 + 8 * 2048;
  unsigned* part2 = part1 + 8 * 2048;
  float* poolc1 = (float*)(part2 + 8 * 2048);               // 8*1024
  float* poolc2 = poolc1 + 8 * 1024;
  float* poolco = poolc2 + 8 * 1024;                        // 8*2048
  unsigned* arena = (unsigned*)(poolco + 8 * 2048);         // 288*512 dwords

  hipMemsetAsync(d_out, 0, 1024 * sizeof(float), stream);
  hipMemsetAsync(part0, 0, 3 * 8 * 2048 * sizeof(unsigned), stream);

  prep_frags<<<N_UNITS, 64, 0, stream>>>(w_in, w1, w2, w3, wo1, wo2, arena);
  k0_kern<<<NBLK, TPB, 0, stream>>>(x, cls, b_in, b1, b2, b3, arena, f3g, part0);
  pool_reduce_kern<64><<<8, 1024, 0, stream>>>(part0, w1 + (size_t)64 * 256, b1 + 64, poolc1);
  kmid_kern<<<NBLK, TPB, 0, stream>>>(f3g, arena, poolc1, part1, cls, cls + NPTS,
                                      b2 + 128, b3 + 128, U_W1_1, U_W2_1, U_W3_1);
  pool_reduce_kern<64><<<8, 1024, 0, stream>>>(part1, w1 + (size_t)2 * 64 * 256, b1 + 128, poolc2);
  kmid_kern<<<NBLK, TPB, 0, stream>>>(f3g, arena, poolc2, part2, cls + NPTS, cls + 2 * NPTS,
                                      b2 + 256, b3 + 256, U_W1_2, U_W2_2, U_W3_2);
  pool_reduce_kern<128><<<8, 1024, 0, stream>>>(part2, wo1, bo1, poolco);
  k3_kern<<<NBLK, TPB, 0, stream>>>(f3g, arena, poolco, cls + 2 * NPTS, bo2, (unsigned*)d_out);
}

// Round 10
// 416.005 us; speedup vs baseline: 2.8419x; 2.7093x over previous
//
#include <hip/hip_runtime.h>

// LapCluster MI355X — round 10: MFMA pipeline, traffic-restructured.
// r9 post-mortem: nt hints were no-ops (FETCH/WRITE identical). Real causes:
// (a) scattered 64B-per-quad D-layout stores -> ~5x HBM write amplification
//     (317MB vs 64MB true; r6 fp32 with 256B stores showed 69MB);
// (b) bfrag re-read the arena per MFMA (2GB instr-level/dispatch) while the
//     streaming write-allocates thrashed the 4MB/XCD L2 (FETCH 526MB).
// Fixes: (1) Nt-per-wave + Mt-loop mapping: each bfrag serves 2-4 MFMAs
// (6.4x less arena traffic); bias/poolc collapse to 1 scalar/lane.
// (2) f3 output staged through LDS planes, written with the inverse of the
// stage-in transform -> fully-coalesced 16B/lane stores. (3) int4 cluster-id
// loads. Math unchanged: 16x16x32 bf16 MFMA, 3-term split (AhBh+AhBl+AlBh).
// A[m=lane&15][k=quad*8+j], B[k=quad*8+j][n=lane&15], D[m=quad*4+r][n=lane&15].
// Pool trick: W*[f3,pool] = W[:,:128]*f3 + poolc[o][cluster]; clusters in
// [0,16); ReLU>=0 -> u32 atomicMax exact.

typedef __attribute__((ext_vector_type(8))) short bf16x8;
typedef __attribute__((ext_vector_type(4))) float f32x4;
typedef __attribute__((ext_vector_type(4))) unsigned u32x4;
typedef __attribute__((ext_vector_type(4))) float f32x4v;

#define MFMA16(a, b, c) __builtin_amdgcn_mfma_f32_16x16x32_bf16((a), (b), (c), 0, 0, 0)

#define TPB 512
#define PT 64
#define NPTS 131072
#define NC 16
#define TILES 4
#define NBLK 512         // 64 blocks/batch

#define FSB 136          // 128-ch plane stride (bf16 units)
#define ASB 72           // 64-ch plane stride
#define XSB 40           // 32-ch (padded x) plane stride

// frag arena units (1 unit = 64 lanes * 8 dwords: [0..3]=hi frag, [4..7]=lo)
#define U_F256 0
#define U_W1_0 16
#define U_W2_0 48
#define U_W3_0 64
#define U_W1_1 96
#define U_W2_1 112
#define U_W3_1 128
#define U_W1_2 160
#define U_W2_2 176
#define U_W3_2 192
#define U_O1   224
#define U_O2   256
#define N_UNITS 288

__device__ __forceinline__ f32x4 relu4(f32x4 a) {
#pragma unroll
  for (int r = 0; r < 4; ++r) a[r] = fmaxf(a[r], 0.f);
  return a;
}

__device__ __forceinline__ bf16x8 afrag(const short* plane, int stride, int mt, int ks) {
  const int lane = threadIdx.x & 63;
  return *reinterpret_cast<const bf16x8*>(
      plane + (mt * 16 + (lane & 15)) * stride + ks * 32 + (lane >> 4) * 8);
}

__device__ __forceinline__ void bfrag(const unsigned* __restrict__ arena, int unit,
                                      bf16x8& h, bf16x8& l) {
  const bf16x8* p = reinterpret_cast<const bf16x8*>(
      arena + ((size_t)unit * 64 + (threadIdx.x & 63)) * 8);
  h = p[0];
  l = p[1];
}

// write already-relu'd D (4 regs = pts mt*16 + quad*4 + r) as hi/lo bf16
__device__ __forceinline__ void store_planes(short* hp, short* lp, int stride,
                                             int mt, int n, f32x4 d) {
  const int m0 = mt * 16 + ((threadIdx.x & 63) >> 4) * 4;
#pragma unroll
  for (int r = 0; r < 4; ++r) {
    unsigned uv = __float_as_uint(d[r]);
    unsigned hm = uv & 0xFFFF0000u;
    float lo = d[r] - __uint_as_float(hm);
    hp[(m0 + r) * stride + n] = (short)(hm >> 16);
    lp[(m0 + r) * stride + n] = (short)(__float_as_uint(lo) >> 16);
  }
}

// coalesced stage-in: packed f3 (hi<<16|lo) -> hi/lo LDS planes
__device__ __forceinline__ void stage_f3(const unsigned* __restrict__ f3g, int tile0,
                                         short* Fhi, short* Flo, int tid) {
  const u32x4* src = reinterpret_cast<const u32x4*>(f3g + (size_t)tile0 * 128);
#pragma unroll
  for (int rr = 0; rr < 4; ++rr) {
    const int idx = rr * TPB + tid;
    const u32x4 p = __builtin_nontemporal_load(src + idx);
    const int pt = idx >> 5, c4 = (idx & 31) * 4;
    uint2 hd, ld;
    hd.x = (p.y & 0xFFFF0000u) | (p.x >> 16);
    hd.y = (p.w & 0xFFFF0000u) | (p.z >> 16);
    ld.x = (p.y << 16) | (p.x & 0xFFFFu);
    ld.y = (p.w << 16) | (p.z & 0xFFFFu);
    *reinterpret_cast<uint2*>(&Fhi[pt * FSB + c4]) = hd;
    *reinterpret_cast<uint2*>(&Flo[pt * FSB + c4]) = ld;
  }
}

// coalesced pack-write: hi/lo planes -> packed f3 global (inverse of stage_f3)
__device__ __forceinline__ void write_f3(unsigned* __restrict__ f3g, int tile0,
                                         const short* Fhi, const short* Flo, int tid) {
  u32x4* dst = reinterpret_cast<u32x4*>(f3g + (size_t)tile0 * 128);
#pragma unroll
  for (int rr = 0; rr < 4; ++rr) {
    const int idx = rr * TPB + tid;
    const int pt = idx >> 5, c4 = (idx & 31) * 4;
    const uint2 hd = *reinterpret_cast<const uint2*>(&Fhi[pt * FSB + c4]);
    const uint2 ld = *reinterpret_cast<const uint2*>(&Flo[pt * FSB + c4]);
    u32x4 p;
    p.x = (hd.x << 16) | (ld.x & 0xFFFFu);
    p.y = (hd.x & 0xFFFF0000u) | (ld.x >> 16);
    p.z = (hd.y << 16) | (ld.y & 0xFFFFu);
    p.w = (hd.y & 0xFFFF0000u) | (ld.y >> 16);
    __builtin_nontemporal_store(p, dst + idx);
  }
}

// ---- prep: split weights into fragment-ordered hi/lo bf16 arenas
__global__ void __launch_bounds__(64) prep_frags(
    const float* __restrict__ w_in, const float* __restrict__ w1,
    const float* __restrict__ w2, const float* __restrict__ w3,
    const float* __restrict__ wo1, const float* __restrict__ wo2,
    unsigned* __restrict__ arena) {
  const int unit = blockIdx.x;
  const int lane = threadIdx.x;
  const float* W; int KS, Klog, rs, u;
  if (unit < U_W1_0)      { W = w_in;                   u = unit - U_F256; KS = 1; Klog = 28;  rs = 28;  }
  else if (unit < U_W2_0) { W = w1;                     u = unit - U_W1_0; KS = 8; Klog = 256; rs = 256; }
  else if (unit < U_W3_0) { W = w2;                     u = unit - U_W2_0; KS = 2; Klog = 64;  rs = 64;  }
  else if (unit < U_W1_1) { W = w3;                     u = unit - U_W3_0; KS = 4; Klog = 128; rs = 128; }
  else if (unit < U_W2_1) { W = w1 + 64 * 256;          u = unit - U_W1_1; KS = 4; Klog = 128; rs = 256; }
  else if (unit < U_W3_1) { W = w2 + 128 * 64;          u = unit - U_W2_1; KS = 2; Klog = 64;  rs = 64;  }
  else if (unit < U_W1_2) { W = w3 + 128 * 128;         u = unit - U_W3_1; KS = 4; Klog = 128; rs = 128; }
  else if (unit < U_W2_2) { W = w1 + 2 * 64 * 256;      u = unit - U_W1_2; KS = 4; Klog = 128; rs = 256; }
  else if (unit < U_W3_2) { W = w2 + 2 * 128 * 64;      u = unit - U_W2_2; KS = 2; Klog = 64;  rs = 64;  }
  else if (unit < U_O1)   { W = w3 + 2 * 128 * 128;     u = unit - U_W3_2; KS = 4; Klog = 128; rs = 128; }
  else if (unit < U_O2)   { W = wo1;                    u = unit - U_O1;   KS = 4; Klog = 128; rs = 256; }
  else                    { W = wo2;                    u = unit - U_O2;   KS = 4; Klog = 128; rs = 128; }
  const int nt = u / KS, ks = u % KS;
  const int n = nt * 16 + (lane & 15);
  const int k0 = ks * 32 + (lane >> 4) * 8;
  unsigned hiD[4], loD[4];
#pragma unroll
  for (int d = 0; d < 4; ++d) {
    unsigned hu[2], lu[2];
#pragma unroll
    for (int e = 0; e < 2; ++e) {
      const int k = k0 + d * 2 + e;
      float v = (k < Klog) ? W[(size_t)n * rs + k] : 0.f;
      unsigned uv = __float_as_uint(v);
      unsigned hm = uv & 0xFFFF0000u;
      float lo = v - __uint_as_float(hm);
      hu[e] = hm >> 16;
      lu[e] = __float_as_uint(lo) >> 16;
    }
    hiD[d] = hu[0] | (hu[1] << 16);
    loD[d] = lu[0] | (lu[1] << 16);
  }
  unsigned* dst = arena + ((size_t)unit * 64 + lane) * 8;
  *reinterpret_cast<uint4*>(dst)     = make_uint4(hiD[0], hiD[1], hiD[2], hiD[3]);
  *reinterpret_cast<uint4*>(dst + 4) = make_uint4(loD[0], loD[1], loD[2], loD[3]);
}

// ---- per-batch poolc table (fp32)
template<int O>
__global__ void __launch_bounds__(1024) pool_reduce_kern(
    const unsigned* __restrict__ part, const float* __restrict__ W,
    const float* __restrict__ bias, float* __restrict__ poolc_g) {
  __shared__ float pfL[2048];
  __shared__ float Wl[O * 129];
  const int tid = threadIdx.x;
  const int b = blockIdx.x;
  for (int i = tid; i < 2048; i += 1024) pfL[i] = __uint_as_float(part[b * 2048 + i]);
  for (int i = tid; i < O * 128; i += 1024) {
    const int o = i >> 7, k = i & 127;
    Wl[o * 129 + k] = W[o * 256 + 128 + k];
  }
  __syncthreads();
  constexpr int SH = (O == 64) ? 6 : 7;
  for (int e = tid; e < O * 16; e += 1024) {
    const int o = e & (O - 1);
    const int cl = e >> SH;
    float s = bias[o];
    const float* wr = &Wl[o * 129];
    const float* pr = &pfL[cl];
#pragma unroll 4
    for (int k = 0; k < 128; ++k) s = fmaf(wr[k], pr[k * 16], s);
    poolc_g[(size_t)b * (O * 16) + o * 16 + cl] = s;
  }
}

// ---- Stage 0: x -> f256 -> f64(w1[0]) -> f128(w2[0], pooled) -> f3_0(w3[0])
__global__ void __launch_bounds__(TPB, 4) k0_kern(
    const float* __restrict__ x, const int* __restrict__ cls,
    const float* __restrict__ b_in, const float* __restrict__ b1,
    const float* __restrict__ b2, const float* __restrict__ b3,
    const unsigned* __restrict__ arena,
    unsigned* __restrict__ f3g, unsigned* __restrict__ part0) {
  __shared__ short Fhi[PT * FSB], Flo[PT * FSB];
  __shared__ short XA[PT * ASB * 2];               // x planes alias A64 planes
  __shared__ unsigned pool_s[128 * NC];
  short* Xhi = XA;  short* Xlo = XA + PT * XSB;
  short* Ahi = XA;  short* Alo = XA + PT * ASB;
  const int tid = threadIdx.x;
  const int lane = tid & 63, w = tid >> 6, l15 = lane & 15, quad = lane >> 4;
  const int b = blockIdx.x >> 6;
  const int Nt1 = w & 3, mh = w >> 2;
  for (int i = tid; i < 128 * NC; i += TPB) pool_s[i] = 0u;

  float biH[2];
#pragma unroll
  for (int c = 0; c < 2; ++c) biH[c] = b_in[c * 128 + w * 16 + l15];
  const float b1H = b1[Nt1 * 16 + l15];
  const float b2H = b2[w * 16 + l15];
  const float b3H = b3[w * 16 + l15];
  const int n1 = Nt1 * 16 + l15;
  const int n2 = w * 16 + l15;
  const int xpt = (tid < 448) ? tid / 7 : 0;
  const int xc4 = (tid < 448) ? (tid - xpt * 7) * 4 : 0;

  for (int t = 0; t < TILES; ++t) {
    const int tile0 = (blockIdx.x * TILES + t) * PT;
    if (tid < 448) {   // stage x hi/lo
      const f32x4v v = __builtin_nontemporal_load(
          reinterpret_cast<const f32x4v*>(x + (size_t)(tile0 + xpt) * 28 + xc4));
      unsigned h0 = __float_as_uint(v.x) & 0xFFFF0000u, h1 = __float_as_uint(v.y) & 0xFFFF0000u;
      unsigned h2 = __float_as_uint(v.z) & 0xFFFF0000u, h3 = __float_as_uint(v.w) & 0xFFFF0000u;
      uint2 hd, ld;
      hd.x = (h0 >> 16) | h1;
      hd.y = (h2 >> 16) | h3;
      ld.x = (__float_as_uint(v.x - __uint_as_float(h0)) >> 16) |
             (__float_as_uint(v.y - __uint_as_float(h1)) & 0xFFFF0000u);
      ld.y = (__float_as_uint(v.z - __uint_as_float(h2)) >> 16) |
             (__float_as_uint(v.w - __uint_as_float(h3)) & 0xFFFF0000u);
      *reinterpret_cast<uint2*>(&Xhi[xpt * XSB + xc4]) = hd;
      *reinterpret_cast<uint2*>(&Xlo[xpt * XSB + xc4]) = ld;
    } else {           // zero k pads 28..31 (region aliased by A64 last tile)
      const int p = tid - 448;
      *reinterpret_cast<uint2*>(&Xhi[p * XSB + 28]) = make_uint2(0u, 0u);
      *reinterpret_cast<uint2*>(&Xlo[p * XSB + 28]) = make_uint2(0u, 0u);
    }
    int clP[4][4];
#pragma unroll
    for (int Mt = 0; Mt < 4; ++Mt) {
      int4 v = *reinterpret_cast<const int4*>(cls + tile0 + Mt * 16 + quad * 4);
      clP[Mt][0] = v.x; clP[Mt][1] = v.y; clP[Mt][2] = v.z; clP[Mt][3] = v.w;
    }
    __syncthreads();   // B1
    f32x4 a1[2];
#pragma unroll
    for (int m = 0; m < 2; ++m) a1[m] = {b1H, b1H, b1H, b1H};
#pragma unroll 1
    for (int c = 0; c < 2; ++c) {
      // f256 chunk c: wave owns 16 channels (nt = c*8+w), all 4 Mt
      f32x4 f6[4];
#pragma unroll
      for (int Mt = 0; Mt < 4; ++Mt) f6[Mt] = {biH[c], biH[c], biH[c], biH[c]};
      {
        bf16x8 bh, bl;
        bfrag(arena, U_F256 + c * 8 + w, bh, bl);
#pragma unroll
        for (int Mt = 0; Mt < 4; ++Mt) {
          const bf16x8 xah = afrag(Xhi, XSB, Mt, 0), xal = afrag(Xlo, XSB, Mt, 0);
          f6[Mt] = MFMA16(xal, bh, MFMA16(xah, bl, MFMA16(xah, bh, f6[Mt])));
        }
      }
#pragma unroll
      for (int Mt = 0; Mt < 4; ++Mt)
        store_planes(Fhi, Flo, FSB, Mt, n2, relu4(f6[Mt]));
      __syncthreads();   // B2 / B4: chunk staged, X reads done
#pragma unroll
      for (int ks = 0; ks < 4; ++ks) {
        bf16x8 bh, bl;
        bfrag(arena, U_W1_0 + Nt1 * 8 + c * 4 + ks, bh, bl);
#pragma unroll
        for (int m = 0; m < 2; ++m) {
          const bf16x8 ah = afrag(Fhi, FSB, mh * 2 + m, ks), al = afrag(Flo, FSB, mh * 2 + m, ks);
          a1[m] = MFMA16(al, bh, MFMA16(ah, bl, MFMA16(ah, bh, a1[m])));
        }
      }
      if (c == 1) {      // A64 write into XA: all X reads done (post-B4)
#pragma unroll
        for (int m = 0; m < 2; ++m)
          store_planes(Ahi, Alo, ASB, mh * 2 + m, n1, relu4(a1[m]));
      }
      __syncthreads();   // B3 / B5: chunk F-reads done (c=1: A staged)
    }
    // w2: wave owns 16 of 128 out, K=64, all Mt
    f32x4 f2[4];
#pragma unroll
    for (int Mt = 0; Mt < 4; ++Mt) f2[Mt] = {b2H, b2H, b2H, b2H};
#pragma unroll
    for (int ks = 0; ks < 2; ++ks) {
      bf16x8 bh, bl;
      bfrag(arena, U_W2_0 + w * 2 + ks, bh, bl);
#pragma unroll
      for (int Mt = 0; Mt < 4; ++Mt) {
        const bf16x8 ah = afrag(Ahi, ASB, Mt, ks), al = afrag(Alo, ASB, Mt, ks);
        f2[Mt] = MFMA16(al, bh, MFMA16(ah, bl, MFMA16(ah, bh, f2[Mt])));
      }
    }
#pragma unroll
    for (int Mt = 0; Mt < 4; ++Mt) {
      f32x4 d = relu4(f2[Mt]);
#pragma unroll
      for (int r = 0; r < 4; ++r)
        atomicMax(&pool_s[n2 * NC + clP[Mt][r]], __float_as_uint(d[r]));
      store_planes(Fhi, Flo, FSB, Mt, n2, d);   // F w1-readers done at B5
    }
    __syncthreads();   // B6: f128 staged
    // w3: wave owns 16 of 128 out, K=128, all Mt
    f32x4 f3a[4];
#pragma unroll
    for (int Mt = 0; Mt < 4; ++Mt) f3a[Mt] = {b3H, b3H, b3H, b3H};
#pragma unroll
    for (int ks = 0; ks < 4; ++ks) {
      bf16x8 bh, bl;
      bfrag(arena, U_W3_0 + w * 4 + ks, bh, bl);
#pragma unroll
      for (int Mt = 0; Mt < 4; ++Mt) {
        const bf16x8 ah = afrag(Fhi, FSB, Mt, ks), al = afrag(Flo, FSB, Mt, ks);
        f3a[Mt] = MFMA16(al, bh, MFMA16(ah, bl, MFMA16(ah, bh, f3a[Mt])));
      }
    }
    __syncthreads();   // B7: all w3 F-reads done
#pragma unroll
    for (int Mt = 0; Mt < 4; ++Mt)
      store_planes(Fhi, Flo, FSB, Mt, n2, relu4(f3a[Mt]));
    __syncthreads();   // B8: f3 planes staged
    write_f3(f3g, tile0, Fhi, Flo, tid);
    // no end barrier: next x-stage writes XA (readers fenced by B6);
    // next F-writes happen post-next-B1; pack-reads precede next B1.
  }
  for (int i = tid; i < 128 * NC; i += TPB)
    atomicMax(&part0[(size_t)b * 2048 + i], pool_s[i]);
}

// ---- Stages 1,2: f3 -> f64(w1+poolc) -> f128(w2, pooled) -> f3'(w3)
__global__ void __launch_bounds__(TPB, 4) kmid_kern(
    unsigned* __restrict__ f3g, const unsigned* __restrict__ arena,
    const float* __restrict__ poolc_g, unsigned* __restrict__ part_cur,
    const int* __restrict__ clg, const int* __restrict__ clp,
    const float* __restrict__ b2s, const float* __restrict__ b3s,
    int uW1, int uW2, int uW3) {
  __shared__ short Fhi[PT * FSB], Flo[PT * FSB];
  __shared__ short Ahi[PT * ASB], Alo[PT * ASB];
  __shared__ unsigned pool_s[128 * NC];
  const int tid = threadIdx.x;
  const int lane = tid & 63, w = tid >> 6, l15 = lane & 15, quad = lane >> 4;
  const int b = blockIdx.x >> 6;
  const int Nt1 = w & 3, mh = w >> 2;
  for (int i = tid; i < 128 * NC; i += TPB) pool_s[i] = 0u;
  const float b2H = b2s[w * 16 + l15];
  const float b3H = b3s[w * 16 + l15];
  const int n1 = Nt1 * 16 + l15;
  const int n2 = w * 16 + l15;

  for (int t = 0; t < TILES; ++t) {
    const int tile0 = (blockIdx.x * TILES + t) * PT;
    stage_f3(f3g, tile0, Fhi, Flo, tid);
    int clG[2][4], clP[4][4];
#pragma unroll
    for (int m = 0; m < 2; ++m) {
      int4 v = *reinterpret_cast<const int4*>(clg + tile0 + (mh * 2 + m) * 16 + quad * 4);
      clG[m][0] = v.x; clG[m][1] = v.y; clG[m][2] = v.z; clG[m][3] = v.w;
    }
#pragma unroll
    for (int Mt = 0; Mt < 4; ++Mt) {
      int4 v = *reinterpret_cast<const int4*>(clp + tile0 + Mt * 16 + quad * 4);
      clP[Mt][0] = v.x; clP[Mt][1] = v.y; clP[Mt][2] = v.z; clP[Mt][3] = v.w;
    }
    __syncthreads();   // B1: staged
    // w1: wave owns 16 of 64 out (Nt1), K=128, Mt = mh*2+m
    f32x4 a1[2];
#pragma unroll
    for (int m = 0; m < 2; ++m)
#pragma unroll
      for (int r = 0; r < 4; ++r)
        a1[m][r] = poolc_g[(size_t)b * 1024 + n1 * 16 + clG[m][r]];
#pragma unroll
    for (int ks = 0; ks < 4; ++ks) {
      bf16x8 bh, bl;
      bfrag(arena, uW1 + Nt1 * 4 + ks, bh, bl);
#pragma unroll
      for (int m = 0; m < 2; ++m) {
        const bf16x8 ah = afrag(Fhi, FSB, mh * 2 + m, ks), al = afrag(Flo, FSB, mh * 2 + m, ks);
        a1[m] = MFMA16(al, bh, MFMA16(ah, bl, MFMA16(ah, bh, a1[m])));
      }
    }
#pragma unroll
    for (int m = 0; m < 2; ++m)
      store_planes(Ahi, Alo, ASB, mh * 2 + m, n1, relu4(a1[m]));
    __syncthreads();   // B2: A64 staged
    // w2: wave owns 16 of 128 out, K=64, all Mt
    f32x4 f2[4];
#pragma unroll
    for (int Mt = 0; Mt < 4; ++Mt) f2[Mt] = {b2H, b2H, b2H, b2H};
#pragma unroll
    for (int ks = 0; ks < 2; ++ks) {
      bf16x8 bh, bl;
      bfrag(arena, uW2 + w * 2 + ks, bh, bl);
#pragma unroll
      for (int Mt = 0; Mt < 4; ++Mt) {
        const bf16x8 ah = afrag(Ahi, ASB, Mt, ks), al = afrag(Alo, ASB, Mt, ks);
        f2[Mt] = MFMA16(al, bh, MFMA16(ah, bl, MFMA16(ah, bh, f2[Mt])));
      }
    }
#pragma unroll
    for (int Mt = 0; Mt < 4; ++Mt) {
      f32x4 d = relu4(f2[Mt]);
#pragma unroll
      for (int r = 0; r < 4; ++r)
        atomicMax(&pool_s[n2 * NC + clP[Mt][r]], __float_as_uint(d[r]));
      store_planes(Fhi, Flo, FSB, Mt, n2, d);   // F w1-readers done at B2
    }
    __syncthreads();   // B3: f128 staged
    // w3: wave owns 16 of 128 out, K=128, all Mt
    f32x4 f3a[4];
#pragma unroll
    for (int Mt = 0; Mt < 4; ++Mt) f3a[Mt] = {b3H, b3H, b3H, b3H};
#pragma unroll
    for (int ks = 0; ks < 4; ++ks) {
      bf16x8 bh, bl;
      bfrag(arena, uW3 + w * 4 + ks, bh, bl);
#pragma unroll
      for (int Mt = 0; Mt < 4; ++Mt) {
        const bf16x8 ah = afrag(Fhi, FSB, Mt, ks), al = afrag(Flo, FSB, Mt, ks);
        f3a[Mt] = MFMA16(al, bh, MFMA16(ah, bl, MFMA16(ah, bh, f3a[Mt])));
      }
    }
    __syncthreads();   // B4: all w3 F-reads done
#pragma unroll
    for (int Mt = 0; Mt < 4; ++Mt)
      store_planes(Fhi, Flo, FSB, Mt, n2, relu4(f3a[Mt]));
    __syncthreads();   // B5: f3 planes staged
    write_f3(f3g, tile0, Fhi, Flo, tid);
    __syncthreads();   // B6: pack-reads done before next stage-in overwrite
  }
  for (int i = tid; i < 128 * NC; i += TPB)
    atomicMax(&part_cur[(size_t)b * 2048 + i], pool_s[i]);
}

// ---- Head: f3_2 -> o1(wo1+poolco) -> o2(wo2) -> global max
__global__ void __launch_bounds__(TPB, 4) k3_kern(
    const unsigned* __restrict__ f3g, const unsigned* __restrict__ arena,
    const float* __restrict__ poolco_g, const int* __restrict__ clg,
    const float* __restrict__ bo2, unsigned* __restrict__ out) {
  __shared__ short Fhi[PT * FSB], Flo[PT * FSB];
  const int tid = threadIdx.x;
  const int lane = tid & 63, w = tid >> 6, l15 = lane & 15, quad = lane >> 4;
  const int b = blockIdx.x >> 6;
  const float bo2H = bo2[w * 16 + l15];
  const int n2 = w * 16 + l15;
  float omax = 0.f;

  for (int t = 0; t < TILES; ++t) {
    const int tile0 = (blockIdx.x * TILES + t) * PT;
    stage_f3(f3g, tile0, Fhi, Flo, tid);
    int clA[4][4];
#pragma unroll
    for (int Mt = 0; Mt < 4; ++Mt) {
      int4 v = *reinterpret_cast<const int4*>(clg + tile0 + Mt * 16 + quad * 4);
      clA[Mt][0] = v.x; clA[Mt][1] = v.y; clA[Mt][2] = v.z; clA[Mt][3] = v.w;
    }
    __syncthreads();   // B1
    f32x4 o1a[4];
#pragma unroll
    for (int Mt = 0; Mt < 4; ++Mt)
#pragma unroll
      for (int r = 0; r < 4; ++r)
        o1a[Mt][r] = poolco_g[(size_t)b * 2048 + n2 * 16 + clA[Mt][r]];
#pragma unroll
    for (int ks = 0; ks < 4; ++ks) {
      bf16x8 bh, bl;
      bfrag(arena, U_O1 + w * 4 + ks, bh, bl);
#pragma unroll
      for (int Mt = 0; Mt < 4; ++Mt) {
        const bf16x8 ah = afrag(Fhi, FSB, Mt, ks), al = afrag(Flo, FSB, Mt, ks);
        o1a[Mt] = MFMA16(al, bh, MFMA16(ah, bl, MFMA16(ah, bh, o1a[Mt])));
      }
    }
    __syncthreads();   // B2: o1 F-reads done
#pragma unroll
    for (int Mt = 0; Mt < 4; ++Mt)
      store_planes(Fhi, Flo, FSB, Mt, n2, relu4(o1a[Mt]));
    __syncthreads();   // B3: o1 staged
    f32x4 o2a[4];
#pragma unroll
    for (int Mt = 0; Mt < 4; ++Mt) o2a[Mt] = {bo2H, bo2H, bo2H, bo2H};
#pragma unroll
    for (int ks = 0; ks < 4; ++ks) {
      bf16x8 bh, bl;
      bfrag(arena, U_O2 + w * 4 + ks, bh, bl);
#pragma unroll
      for (int Mt = 0; Mt < 4; ++Mt) {
        const bf16x8 ah = afrag(Fhi, FSB, Mt, ks), al = afrag(Flo, FSB, Mt, ks);
        o2a[Mt] = MFMA16(al, bh, MFMA16(ah, bl, MFMA16(ah, bh, o2a[Mt])));
      }
    }
#pragma unroll
    for (int Mt = 0; Mt < 4; ++Mt) {
      f32x4 d = relu4(o2a[Mt]);
      omax = fmaxf(omax, fmaxf(fmaxf(d[0], d[1]), fmaxf(d[2], d[3])));
    }
    __syncthreads();   // B4: o2 F-reads done before next stage-in
  }
  omax = fmaxf(omax, __shfl_xor(omax, 16));
  omax = fmaxf(omax, __shfl_xor(omax, 32));
  if (lane < 16)
    atomicMax(&out[b * 128 + w * 16 + lane], __float_as_uint(omax));
}

extern "C" void kernel_launch(void* const* d_in, const int* in_sizes, int n_in,
                              void* d_out, int out_size, void* d_ws, size_t ws_size,
                              hipStream_t stream) {
  const float* x    = (const float*)d_in[0];
  const int*   cls  = (const int*)d_in[1];
  const float* w_in = (const float*)d_in[2];
  const float* b_in = (const float*)d_in[3];
  const float* w1   = (const float*)d_in[4];
  const float* b1   = (const float*)d_in[5];
  const float* w2   = (const float*)d_in[6];
  const float* b2   = (const float*)d_in[7];
  const float* w3   = (const float*)d_in[8];
  const float* b3   = (const float*)d_in[9];
  const float* wo1  = (const float*)d_in[10];
  const float* bo1  = (const float*)d_in[11];
  const float* wo2  = (const float*)d_in[12];
  const float* bo2  = (const float*)d_in[13];

  char* ws = (char*)d_ws;
  unsigned* f3g = (unsigned*)ws;                            // 64 MB packed hi|lo
  unsigned* part0 = (unsigned*)(ws + ((size_t)64 << 20));   // 3 x 8 KB
  unsigned* part1 = part0 + 8 * 2048;
  unsigned* part2 = part1 + 8 * 2048;
  float* poolc1 = (float*)(part2 + 8 * 2048);               // 8*1024
  float* poolc2 = poolc1 + 8 * 1024;
  float* poolco = poolc2 + 8 * 1024;                        // 8*2048
  unsigned* arena = (unsigned*)(poolco + 8 * 2048);         // 288*512 dwords

  hipMemsetAsync(d_out, 0, 1024 * sizeof(float), stream);
  hipMemsetAsync(part0, 0, 3 * 8 * 2048 * sizeof(unsigned), stream);

  prep_frags<<<N_UNITS, 64, 0, stream>>>(w_in, w1, w2, w3, wo1, wo2, arena);
  k0_kern<<<NBLK, TPB, 0, stream>>>(x, cls, b_in, b1, b2, b3, arena, f3g, part0);
  pool_reduce_kern<64><<<8, 1024, 0, stream>>>(part0, w1 + (size_t)64 * 256, b1 + 64, poolc1);
  kmid_kern<<<NBLK, TPB, 0, stream>>>(f3g, arena, poolc1, part1, cls, cls + NPTS,
                                      b2 + 128, b3 + 128, U_W1_1, U_W2_1, U_W3_1);
  pool_reduce_kern<64><<<8, 1024, 0, stream>>>(part1, w1 + (size_t)2 * 64 * 256, b1 + 128, poolc2);
  kmid_kern<<<NBLK, TPB, 0, stream>>>(f3g, arena, poolc2, part2, cls + NPTS, cls + 2 * NPTS,
                                      b2 + 256, b3 + 256, U_W1_2, U_W2_2, U_W3_2);
  pool_reduce_kern<128><<<8, 1024, 0, stream>>>(part2, wo1, bo1, poolco);
  k3_kern<<<NBLK, TPB, 0, stream>>>(f3g, arena, poolco, cls + 2 * NPTS, bo2, (unsigned*)d_out);
}